// Round 1
// baseline (483.348 us; speedup 1.0000x reference)
//
#include <hip/hip_runtime.h>
#include <math.h>

#define DDIM 1024
#define DVDIM 8
#define TPB 256
#define EPS_K 1e-6f
#define EPS_NORM 1e-6f

// Transpose Wv (DV, D) -> WvT (D, DV) so the main kernel can float4-load it.
__global__ void wv_transpose_kernel(const float* __restrict__ Wv,
                                    float* __restrict__ WvT) {
    int i = blockIdx.x * blockDim.x + threadIdx.x;  // 0 .. D*DV-1
    if (i < DDIM * DVDIM) {
        int d = i >> 3;       // row in WvT
        int j = i & 7;        // col in WvT
        WvT[i] = Wv[j * DDIM + d];
    }
}

__launch_bounds__(TPB)
__global__ void delta_residual_kernel(const float* __restrict__ X,
                                      const float* __restrict__ sub,
                                      const float* __restrict__ xin,
                                      const float* __restrict__ gnw,
                                      const float* __restrict__ gw,
                                      const float* __restrict__ gb,
                                      const float* __restrict__ WvT,
                                      float* __restrict__ out) {
    const int token = blockIdx.x;
    const int tid = threadIdx.x;
    const int lane = tid & 63;
    const int wv = tid >> 6;                  // wave id, 0..3
    const long rowX = (long)token * (DDIM * DVDIM);
    const long rowD = (long)token * DDIM;

    __shared__ float sl_lds[DDIM];            // raw sublayer row
    __shared__ float red[4][11];              // per-wave partials
    __shared__ float fin[19];                 // [0]=ssk [1]=ssx [2]=gdot [3..10]=v [11..18]=kTXraw

    // ---- issue X loads first: 8 x float4 per thread, held in registers ----
    const float4* X4 = (const float4*)(X + rowX);
    float4 xr[8];
#pragma unroll
    for (int u = 0; u < 8; ++u) xr[u] = X4[tid + TPB * u];

    // ---- sublayer row: 4 floats/thread -> LDS + sum of squares ----
    float4 sl4 = ((const float4*)(sub + rowD))[tid];
    ((float4*)sl_lds)[tid] = sl4;
    float pssk = sl4.x * sl4.x + sl4.y * sl4.y + sl4.z * sl4.z + sl4.w * sl4.w;

    // ---- x_in row: sumsq, gate dot, v partials ----
    float4 x4 = ((const float4*)(xin + rowD))[tid];
    float pssx = x4.x * x4.x + x4.y * x4.y + x4.z * x4.z + x4.w * x4.w;
    float4 gnw4 = ((const float4*)gnw)[tid];
    float4 gw4 = ((const float4*)gw)[tid];
    float pgdot = x4.x * gnw4.x * gw4.x + x4.y * gnw4.y * gw4.y +
                  x4.z * gnw4.z * gw4.z + x4.w * gnw4.w * gw4.w;

    float pv[8] = {0, 0, 0, 0, 0, 0, 0, 0};
    {
        const float4* W4 = (const float4*)WvT;
        float xs[4] = {x4.x, x4.y, x4.z, x4.w};
#pragma unroll
        for (int u2 = 0; u2 < 4; ++u2) {
            int d = 4 * tid + u2;
            float4 wa = W4[2 * d];
            float4 wb = W4[2 * d + 1];
            pv[0] += xs[u2] * wa.x;
            pv[1] += xs[u2] * wa.y;
            pv[2] += xs[u2] * wa.z;
            pv[3] += xs[u2] * wa.w;
            pv[4] += xs[u2] * wb.x;
            pv[5] += xs[u2] * wb.y;
            pv[6] += xs[u2] * wb.z;
            pv[7] += xs[u2] * wb.w;
        }
    }

    // ---- phase A reduction: 11 scalars ----
    {
        float a[11] = {pssk, pssx, pgdot, pv[0], pv[1], pv[2], pv[3],
                       pv[4], pv[5], pv[6], pv[7]};
#pragma unroll
        for (int i = 0; i < 11; ++i) {
            float t = a[i];
#pragma unroll
            for (int off = 32; off > 0; off >>= 1) t += __shfl_down(t, off);
            if (lane == 0) red[wv][i] = t;
        }
    }
    __syncthreads();
    if (tid < 11) fin[tid] = red[0][tid] + red[1][tid] + red[2][tid] + red[3][tid];
    __syncthreads();

    const float ssk = fin[0];
    const float ssx = fin[1];
    const float gdot = fin[2];

    const float norm = sqrtf(ssk);
    const float kscale = 1.0f / (fmaxf(norm, EPS_K) * 32.0f);  // /max(norm,eps)/sqrt(D)
    const float rms = rsqrtf(ssx * (1.0f / (float)DDIM) + EPS_NORM);
    const float logit = gdot * rms + gb[0];
    const float beta = 2.0f / (1.0f + expf(-logit));

    // ---- phase B: raw kTX sums (kscale applied after reduce) ----
    float kacc[8] = {0, 0, 0, 0, 0, 0, 0, 0};
    const int h = (tid & 1) * 4;  // f = tid + 256u -> f&1 == tid&1, constant
#pragma unroll
    for (int u = 0; u < 8; ++u) {
        int f = tid + TPB * u;
        int d = f >> 1;
        float sld = sl_lds[d];
        kacc[h + 0] += sld * xr[u].x;
        kacc[h + 1] += sld * xr[u].y;
        kacc[h + 2] += sld * xr[u].z;
        kacc[h + 3] += sld * xr[u].w;
    }
    {
#pragma unroll
        for (int i = 0; i < 8; ++i) {
            float t = kacc[i];
#pragma unroll
            for (int off = 32; off > 0; off >>= 1) t += __shfl_down(t, off);
            if (lane == 0) red[wv][i] = t;
        }
    }
    __syncthreads();
    if (tid < 8) fin[11 + tid] = red[0][tid] + red[1][tid] + red[2][tid] + red[3][tid];
    __syncthreads();

    // ---- epilogue: out = X + sl[d] * (beta*kscale*corr[j]) ----
    float bc[8];
#pragma unroll
    for (int j = 0; j < 8; ++j) {
        float ktx = fin[11 + j] * kscale;
        float corr = fin[3 + j] - ktx;
        bc[j] = beta * kscale * corr;
    }

    float4* O4 = (float4*)(out + rowX);
#pragma unroll
    for (int u = 0; u < 8; ++u) {
        int f = tid + TPB * u;
        int d = f >> 1;
        float sld = sl_lds[d];
        float4 o;
        o.x = xr[u].x + sld * bc[h + 0];
        o.y = xr[u].y + sld * bc[h + 1];
        o.z = xr[u].z + sld * bc[h + 2];
        o.w = xr[u].w + sld * bc[h + 3];
        O4[f] = o;
    }
}

extern "C" void kernel_launch(void* const* d_in, const int* in_sizes, int n_in,
                              void* d_out, int out_size, void* d_ws, size_t ws_size,
                              hipStream_t stream) {
    const float* X   = (const float*)d_in[0];
    const float* sub = (const float*)d_in[1];
    const float* xin = (const float*)d_in[2];
    const float* gnw = (const float*)d_in[3];
    const float* gw  = (const float*)d_in[4];
    const float* gb  = (const float*)d_in[5];
    const float* Wv  = (const float*)d_in[6];
    float* out = (float*)d_out;
    float* WvT = (float*)d_ws;  // D*DV floats = 32 KiB

    const int tokens = in_sizes[0] / (DDIM * DVDIM);  // B*T

    wv_transpose_kernel<<<(DDIM * DVDIM + TPB - 1) / TPB, TPB, 0, stream>>>(Wv, WvT);
    delta_residual_kernel<<<tokens, TPB, 0, stream>>>(X, sub, xin, gnw, gw, gb, WvT, out);
}